// Round 8
// baseline (511.840 us; speedup 1.0000x reference)
//
#include <hip/hip_runtime.h>
#include <math.h>

// Problem constants (fixed by reference)
#define Z 2
#define NPT 256     // points per batch
#define CHN 16      // channels
#define NH 2        // heads
#define NBK 10      // key/conv radial basis
#define HD 100      // radial hidden width
#define NBV 3       // value radial basis
#define G 512       // radial table grid points (all tables ~2 MB, L2-resident)
// Unified table domain [0, VD]. Key/conv radials are exactly 0 beyond
// 5+5/9 (all cosine bases zero); value radial support extends to 7.5.
// At d >= VD all three radials are exactly 0, so the gi>=G-1 clamp is exact.
#define VD 7.5f

__device__ __forceinline__ float swishf(float x) {
    return x / (1.0f + __expf(-x));
}

// ---------------------------------------------------------------------------
// Kernel 1: build radial tables as interleaved float2 {T[g], T[g+1]};
// also zeroes d_out (block 0) so the mega kernel can atomicAdd into it.
// reps: 0,1 = key heads (2-layer); 2 = conv (2-layer); 3,4 = value (1-layer).
// 16 grid pts per block; grid = 5*32 = 160 blocks x 128 threads.
// ---------------------------------------------------------------------------
__global__ __launch_bounds__(128)
void build_tables(const float* __restrict__ K0, const float* __restrict__ K1,
                  const float* __restrict__ C0, const float* __restrict__ C1,
                  const float* __restrict__ V0,
                  float* __restrict__ TKf, float* __restrict__ TCf,
                  float* __restrict__ TVf, float* __restrict__ out_zero) {
    int bid = blockIdx.x;
    int rep = bid >> 5;              // 0..4
    int g0  = (bid & 31) * 16;
    int t   = threadIdx.x;

    if (bid == 0) {                  // zero d_out: Z*NPT*CHN = 8192 floats
        float4* o4 = (float4*)out_zero;
        #pragma unroll
        for (int k = 0; k < 16; ++k) o4[k*128 + t] = make_float4(0.f,0.f,0.f,0.f);
    }

    if (rep >= 3) {                  // value heads: 1-layer radial
        const float* W0v = V0 + (rep - 3)*NBV*HD;
        float* Tf = TVf + (size_t)(rep - 3)*2*G*HD;
        if (t < HD) {
            #pragma unroll
            for (int k = 0; k < 16; ++k) {
                int gg = g0 + k;
                float d = gg * (VD / (float)(G-1));
                float s = 0.f;
                #pragma unroll
                for (int q = 0; q < NBV; ++q) {
                    float diff = (d - q*2.5f) * 0.4f;
                    float bq = (fabsf(diff) < 1.0f) ? __cosf(1.57079632679f*diff) : 0.f;
                    s += bq * W0v[q*HD + t];
                }
                float v = swishf(s);
                Tf[2*((size_t)gg*HD + t) + 0] = v;
                if (gg > 0) Tf[2*((size_t)(gg-1)*HD + t) + 1] = v;
            }
        }
        return;
    }

    const float* W0 = (rep == 0) ? K0 : (rep == 1) ? (K0 + NBK*HD) : C0;
    const float* W1 = (rep == 0) ? K1 : (rep == 1) ? (K1 + HD*HD)  : C1;
    float* Tf       = (rep == 0) ? TKf : (rep == 1) ? (TKf + 2*(size_t)G*HD) : TCf;

    __shared__ float s_b10[16][NBK];
    __shared__ __align__(16) float s_h1[HD*16];   // [n][k]

    if (t < 16) {
        float d = (g0 + t) * (VD / (float)(G-1));
        #pragma unroll
        for (int q = 0; q < NBK; ++q) {
            float diff = (d - q*(5.0f/9.0f)) * 1.8f;
            s_b10[t][q] = (fabsf(diff) < 1.0f) ? __cosf(1.57079632679f*diff) : 0.f;
        }
    }
    __syncthreads();
    if (t < HD) {
        int n = t;
        float w[NBK];
        #pragma unroll
        for (int q = 0; q < NBK; ++q) w[q] = W0[q*HD + n];
        #pragma unroll
        for (int k = 0; k < 16; ++k) {
            float s = 0.f;
            #pragma unroll
            for (int q = 0; q < NBK; ++q) s += s_b10[k][q] * w[q];
            s_h1[n*16 + k] = swishf(s);
        }
    }
    __syncthreads();
    if (t < HD) {
        int m = t;
        float acc[16];
        #pragma unroll
        for (int k = 0; k < 16; ++k) acc[k] = 0.f;
        const float* w1 = W1 + m;
        #pragma unroll 2
        for (int n = 0; n < HD; ++n) {
            float w = w1[n*HD];                            // coalesced across m
            const float4* hp = (const float4*)&s_h1[n*16]; // broadcast
            float4 x0 = hp[0], x1 = hp[1], x2 = hp[2], x3 = hp[3];
            acc[0]+=x0.x*w;  acc[1]+=x0.y*w;  acc[2]+=x0.z*w;  acc[3]+=x0.w*w;
            acc[4]+=x1.x*w;  acc[5]+=x1.y*w;  acc[6]+=x1.z*w;  acc[7]+=x1.w*w;
            acc[8]+=x2.x*w;  acc[9]+=x2.y*w;  acc[10]+=x2.z*w; acc[11]+=x2.w*w;
            acc[12]+=x3.x*w; acc[13]+=x3.y*w; acc[14]+=x3.z*w; acc[15]+=x3.w*w;
        }
        #pragma unroll
        for (int k = 0; k < 16; ++k) {
            float v = swishf(acc[k]);
            int gg = g0 + k;
            Tf[2*((size_t)gg*HD + m) + 0] = v;
            if (gg > 0) Tf[2*((size_t)(gg-1)*HD + m) + 1] = v;
        }
    }
}

// ---------------------------------------------------------------------------
// Kernel 2: mega — q/Gq + scores + softmax + value-U + Vf epilogue + CONV
// SCATTER. One block per (z,h,a) = 1024 blocks x 256 threads.
// The final conv is linear in the attention output, so each block scatters
// its own head's contribution: out[a',i] += sum_m h2c(d_{a',a})[m] * W[m,i],
// W[m,i] = sum_j Cf[m][i*16+j] * o[j]. d(a',a) == d(a,a') -> s_gi/s_fr reuse.
// ---------------------------------------------------------------------------
__global__ __launch_bounds__(256, 4)
void mega_attn(const float* __restrict__ f, const float* __restrict__ xyz,
               const float* __restrict__ Wq, const float* __restrict__ Kf,
               const float* __restrict__ Vf, const float* __restrict__ Cf,
               const float2* __restrict__ TK2, const float2* __restrict__ TV2,
               const float2* __restrict__ TC2, float* __restrict__ out) {
    int bid = blockIdx.x;            // (z*NH + h)*NPT + a
    int a  = bid & 255;
    int zh = bid >> 8;
    int h  = zh & 1;
    int z  = zh >> 1;
    int t  = threadIdx.x;

    __shared__ __align__(16) float s_f[NPT*CHN];   // 16384 B
    __shared__ __align__(16) float s_gu[HD*20];    // 8000 B  gq -> U -> W
    __shared__ int   s_gi[NPT];                    // 1024 B
    __shared__ float s_fr[NPT];                    // 1024 B
    __shared__ float s_sc[NPT];                    // 1024 B  scores then p
    __shared__ float s_red[8];
    __shared__ float s_red2[256];                  // q early; Vf partials late
    __shared__ float s_o[16];                      // block's attn output (head h)

    // phase 1: stage features, per-b geometry, q, gq
    {
        const float4* fz = (const float4*)(f + (size_t)z*NPT*CHN);
        float4* sf = (float4*)s_f;
        for (int i = t; i < NPT*CHN/4; i += 256) sf[i] = fz[i];
    }
    {
        float ax = xyz[(z*NPT + a)*3 + 0];
        float ay = xyz[(z*NPT + a)*3 + 1];
        float az = xyz[(z*NPT + a)*3 + 2];
        int b = t;
        float dx = xyz[(z*NPT + b)*3 + 0] - ax;
        float dy = xyz[(z*NPT + b)*3 + 1] - ay;
        float dz = xyz[(z*NPT + b)*3 + 2] - az;
        float d = sqrtf(dx*dx + dy*dy + dz*dz + 1e-12f);
        float fd = d * ((float)(G-1) / VD);
        int   gi = (int)fd;
        float fr = fd - (float)gi;
        if (gi >= G-1) { gi = G-2; fr = 1.0f; }    // beyond support -> exact 0
        s_gi[b] = gi; s_fr[b] = fr;
    }
    __syncthreads();
    if (t < CHN) {       // q[o] = sum_i f[a,i] * Wq[h][o][i]
        float s = 0.f;
        const float* wq = Wq + (h*CHN + t)*CHN;
        #pragma unroll
        for (int i = 0; i < CHN; ++i) s += s_f[a*CHN + i] * wq[i];
        s_red2[t] = s;
    }
    __syncthreads();
    {   // gq[m][j] = sum_i Kf[h][m][i*16+j] * q[i]
        const float* kf = Kf + (size_t)h*HD*256;
        for (int idx = t; idx < HD*CHN; idx += 256) {
            int m = idx >> 4, j = idx & 15;
            float s = 0.f;
            #pragma unroll
            for (int i = 0; i < CHN; ++i) s += kf[m*256 + i*16 + j] * s_red2[i];
            s_gu[m*20 + j] = s;
        }
    }
    __syncthreads();

    // phase 2: scores. wave w owns b in [w*64, w*64+64); lane covers m, m+64.
    {
        int lane = t & 63, w = t >> 6;
        int m2 = lane + 64;
        bool hasm2 = (m2 < HD);
        float gq1[16], gq2[16];
        {
            const float4* gp = (const float4*)&s_gu[lane*20];
            float4 g0 = gp[0], g1 = gp[1], g2 = gp[2], g3 = gp[3];
            gq1[0]=g0.x;  gq1[1]=g0.y;  gq1[2]=g0.z;  gq1[3]=g0.w;
            gq1[4]=g1.x;  gq1[5]=g1.y;  gq1[6]=g1.z;  gq1[7]=g1.w;
            gq1[8]=g2.x;  gq1[9]=g2.y;  gq1[10]=g2.z; gq1[11]=g2.w;
            gq1[12]=g3.x; gq1[13]=g3.y; gq1[14]=g3.z; gq1[15]=g3.w;
        }
        #pragma unroll
        for (int j = 0; j < 16; ++j) gq2[j] = 0.f;
        if (hasm2) {
            const float4* gp = (const float4*)&s_gu[m2*20];
            float4 g0 = gp[0], g1 = gp[1], g2 = gp[2], g3 = gp[3];
            gq2[0]=g0.x;  gq2[1]=g0.y;  gq2[2]=g0.z;  gq2[3]=g0.w;
            gq2[4]=g1.x;  gq2[5]=g1.y;  gq2[6]=g1.z;  gq2[7]=g1.w;
            gq2[8]=g2.x;  gq2[9]=g2.y;  gq2[10]=g2.z; gq2[11]=g2.w;
            gq2[12]=g3.x; gq2[13]=g3.y; gq2[14]=g3.z; gq2[15]=g3.w;
        }
        const float2* tk = TK2 + (size_t)h*G*HD;
        int bbase = w*64;
        float2 ta0, tb0, ta1, tb1;
        {
            int g0i = s_gi[bbase], g1i = s_gi[bbase+1];
            ta0 = tk[(size_t)g0i*HD + lane];
            tb0 = hasm2 ? tk[(size_t)g0i*HD + m2] : make_float2(0.f, 0.f);
            ta1 = tk[(size_t)g1i*HD + lane];
            tb1 = hasm2 ? tk[(size_t)g1i*HD + m2] : make_float2(0.f, 0.f);
        }
        #pragma unroll 1
        for (int bb = 0; bb < 64; bb += 2) {
            int b0 = bbase + bb, b1 = b0 + 1;
            float fr0 = s_fr[b0], fr1 = s_fr[b1];
            float2 ca0 = ta0, cb0 = tb0, ca1 = ta1, cb1 = tb1;
            if (bb + 2 < 64) {
                int gn0 = s_gi[b0 + 2], gn1 = s_gi[b0 + 3];
                ta0 = tk[(size_t)gn0*HD + lane];
                tb0 = hasm2 ? tk[(size_t)gn0*HD + m2] : make_float2(0.f, 0.f);
                ta1 = tk[(size_t)gn1*HD + lane];
                tb1 = hasm2 ? tk[(size_t)gn1*HD + m2] : make_float2(0.f, 0.f);
            }
            float h2a0 = ca0.x + fr0*(ca0.y - ca0.x);
            float h2b0 = cb0.x + fr0*(cb0.y - cb0.x);
            float h2a1 = ca1.x + fr1*(ca1.y - ca1.x);
            float h2b1 = cb1.x + fr1*(cb1.y - cb1.x);
            const float4* fp0 = (const float4*)&s_f[b0*CHN];
            const float4* fp1 = (const float4*)&s_f[b1*CHN];
            float4 x0 = fp0[0], x1 = fp0[1], x2 = fp0[2], x3 = fp0[3];
            float4 y0 = fp1[0], y1 = fp1[1], y2 = fp1[2], y3 = fp1[3];
            float gfa0 = gq1[0]*x0.x + gq1[1]*x0.y + gq1[2]*x0.z + gq1[3]*x0.w
                       + gq1[4]*x1.x + gq1[5]*x1.y + gq1[6]*x1.z + gq1[7]*x1.w
                       + gq1[8]*x2.x + gq1[9]*x2.y + gq1[10]*x2.z + gq1[11]*x2.w
                       + gq1[12]*x3.x + gq1[13]*x3.y + gq1[14]*x3.z + gq1[15]*x3.w;
            float gfb0 = gq2[0]*x0.x + gq2[1]*x0.y + gq2[2]*x0.z + gq2[3]*x0.w
                       + gq2[4]*x1.x + gq2[5]*x1.y + gq2[6]*x1.z + gq2[7]*x1.w
                       + gq2[8]*x2.x + gq2[9]*x2.y + gq2[10]*x2.z + gq2[11]*x2.w
                       + gq2[12]*x3.x + gq2[13]*x3.y + gq2[14]*x3.z + gq2[15]*x3.w;
            float gfa1 = gq1[0]*y0.x + gq1[1]*y0.y + gq1[2]*y0.z + gq1[3]*y0.w
                       + gq1[4]*y1.x + gq1[5]*y1.y + gq1[6]*y1.z + gq1[7]*y1.w
                       + gq1[8]*y2.x + gq1[9]*y2.y + gq1[10]*y2.z + gq1[11]*y2.w
                       + gq1[12]*y3.x + gq1[13]*y3.y + gq1[14]*y3.z + gq1[15]*y3.w;
            float gfb1 = gq2[0]*y0.x + gq2[1]*y0.y + gq2[2]*y0.z + gq2[3]*y0.w
                       + gq2[4]*y1.x + gq2[5]*y1.y + gq2[6]*y1.z + gq2[7]*y1.w
                       + gq2[8]*y2.x + gq2[9]*y2.y + gq2[10]*y2.z + gq2[11]*y2.w
                       + gq2[12]*y3.x + gq2[13]*y3.y + gq2[14]*y3.z + gq2[15]*y3.w;
            float pp0 = h2a0*gfa0 + h2b0*gfb0;
            float pp1 = h2a1*gfa1 + h2b1*gfb1;
            float u0 = __shfl_xor(pp0, 32);
            float u1 = __shfl_xor(pp1, 32);
            float mm = (lane < 32) ? (pp0 + u0) : (pp1 + u1);
            mm += __shfl_xor(mm, 16);
            mm += __shfl_xor(mm, 8);
            mm += __shfl_xor(mm, 4);
            mm += __shfl_xor(mm, 2);
            mm += __shfl_xor(mm, 1);
            if (lane == 0)  s_sc[b0] = mm * (1.0f/16.0f);
            if (lane == 32) s_sc[b1] = mm * (1.0f/16.0f);
        }
    }
    __syncthreads();

    // phase 3: softmax over 256 scores
    {
        float v = s_sc[t];
        float mx = v;
        #pragma unroll
        for (int off = 32; off >= 1; off >>= 1) mx = fmaxf(mx, __shfl_xor(mx, off));
        int wid = t >> 6;
        if ((t & 63) == 0) s_red[wid] = mx;
        __syncthreads();
        mx = fmaxf(fmaxf(s_red[0], s_red[1]), fmaxf(s_red[2], s_red[3]));
        float e = __expf(v - mx);
        float s = e;
        #pragma unroll
        for (int off = 32; off >= 1; off >>= 1) s += __shfl_xor(s, off);
        if ((t & 63) == 0) s_red[4 + wid] = s;
        __syncthreads();
        float tot = s_red[4] + s_red[5] + s_red[6] + s_red[7];
        s_sc[t] = e / tot;
    }
    __syncthreads();

    // phase 4: U[m,j] = sum_b p_b * h1v(d_b)[m] * f[b,j]  via TV lerp
    {
        int mh = t & 127, half = t >> 7;
        float U[16];
        #pragma unroll
        for (int j = 0; j < 16; ++j) U[j] = 0.f;
        if (mh < HD) {
            const float2* tv = TV2 + (size_t)h*G*HD;
            int bbase = half*128;
            float2 tc = tv[(size_t)s_gi[bbase]*HD + mh];
            #pragma unroll 2
            for (int bb = 0; bb < 128; ++bb) {
                int b = bbase + bb;
                float fr = s_fr[b];
                float2 cur = tc;
                if (bb + 1 < 128) tc = tv[(size_t)s_gi[b+1]*HD + mh];
                float hv = cur.x + fr*(cur.y - cur.x);
                float t1 = s_sc[b] * hv;
                const float4* fp = (const float4*)&s_f[b*CHN];
                float4 f0 = fp[0], f1 = fp[1], f2 = fp[2], f3 = fp[3];
                U[0]+=t1*f0.x;  U[1]+=t1*f0.y;  U[2]+=t1*f0.z;  U[3]+=t1*f0.w;
                U[4]+=t1*f1.x;  U[5]+=t1*f1.y;  U[6]+=t1*f1.z;  U[7]+=t1*f1.w;
                U[8]+=t1*f2.x;  U[9]+=t1*f2.y;  U[10]+=t1*f2.z; U[11]+=t1*f2.w;
                U[12]+=t1*f3.x; U[13]+=t1*f3.y; U[14]+=t1*f3.z; U[15]+=t1*f3.w;
            }
        }
        if (half == 1 && mh < HD) {
            #pragma unroll
            for (int j = 0; j < 16; ++j) s_gu[mh*20 + j] = U[j];
        }
        __syncthreads();
        if (half == 0 && mh < HD) {
            #pragma unroll
            for (int j = 0; j < 16; ++j) s_gu[mh*20 + j] += U[j];
        }
    }
    __syncthreads();
    {   // epilogue: o[i] = sum_{m,j} U[m,j] * Vf[h][m][i*16+j]
        int i = t & 15, ms = t >> 4;
        float acc = 0.f;
        for (int m = ms; m < HD; m += 16) {
            const float* vf = Vf + ((size_t)h*HD + m)*256 + i*16;
            const float* Um = &s_gu[m*20];
            #pragma unroll
            for (int j = 0; j < 16; ++j) acc += Um[j] * vf[j];
        }
        s_red2[ms*16 + i] = acc;
    }
    __syncthreads();
    if (t < 16) {
        float s = 0.f;
        #pragma unroll
        for (int ms = 0; ms < 16; ++ms) s += s_red2[ms*16 + t];
        s_o[t] = s;
    }
    __syncthreads();

    // phase 5: conv scatter. W[m,i] = sum_j Cf[m][i*16+j]*o[j]  (overwrite s_gu)
    for (int idx = t; idx < HD*CHN; idx += 256) {
        int m = idx >> 4, i = idx & 15;
        const float* cf = Cf + (size_t)m*256 + i*16;
        float s = 0.f;
        #pragma unroll
        for (int j = 0; j < 16; ++j) s += cf[j] * s_o[j];
        s_gu[m*16 + i] = s;          // stride 16, float4-aligned rows
    }
    __syncthreads();
    {   // thread t owns target a' = t: out[z,a',i] += sum_m h2c(d_{a',a})[m]*W[m,i]
        int gi = s_gi[t];
        float fr = s_fr[t];
        const float4* row = (const float4*)(TC2 + (size_t)gi*HD);   // 50 float4
        float acc[16];
        #pragma unroll
        for (int i = 0; i < 16; ++i) acc[i] = 0.f;
        #pragma unroll 2
        for (int q = 0; q < 50; ++q) {
            float4 tt = row[q];      // {T[g][2q],T[g+1][2q],T[g][2q+1],T[g+1][2q+1]}
            float h2a = tt.x + fr*(tt.y - tt.x);   // m = 2q
            float h2b = tt.z + fr*(tt.w - tt.z);   // m = 2q+1
            const float4* wa = (const float4*)&s_gu[(2*q  )*16];  // broadcast
            const float4* wb = (const float4*)&s_gu[(2*q+1)*16];
            float4 w0 = wa[0], w1 = wa[1], w2 = wa[2], w3 = wa[3];
            float4 v0 = wb[0], v1 = wb[1], v2 = wb[2], v3 = wb[3];
            acc[0] += h2a*w0.x + h2b*v0.x;  acc[1] += h2a*w0.y + h2b*v0.y;
            acc[2] += h2a*w0.z + h2b*v0.z;  acc[3] += h2a*w0.w + h2b*v0.w;
            acc[4] += h2a*w1.x + h2b*v1.x;  acc[5] += h2a*w1.y + h2b*v1.y;
            acc[6] += h2a*w1.z + h2b*v1.z;  acc[7] += h2a*w1.w + h2b*v1.w;
            acc[8] += h2a*w2.x + h2b*v2.x;  acc[9] += h2a*w2.y + h2b*v2.y;
            acc[10]+= h2a*w2.z + h2b*v2.z;  acc[11]+= h2a*w2.w + h2b*v2.w;
            acc[12]+= h2a*w3.x + h2b*v3.x;  acc[13]+= h2a*w3.y + h2b*v3.y;
            acc[14]+= h2a*w3.z + h2b*v3.z;  acc[15]+= h2a*w3.w + h2b*v3.w;
        }
        float* outp = out + ((size_t)z*NPT + t)*CHN;
        #pragma unroll
        for (int i = 0; i < 16; ++i) atomicAdd(outp + i, acc[i]);
    }
}

// ---------------------------------------------------------------------------
extern "C" void kernel_launch(void* const* d_in, const int* in_sizes, int n_in,
                              void* d_out, int out_size, void* d_ws, size_t ws_size,
                              hipStream_t stream) {
    const float* f   = (const float*)d_in[0];
    const float* xyz = (const float*)d_in[1];
    const float* Wq  = (const float*)d_in[2];
    const float* K0  = (const float*)d_in[3];
    const float* K1  = (const float*)d_in[4];
    const float* Kf  = (const float*)d_in[5];
    const float* V0  = (const float*)d_in[6];
    const float* Vf  = (const float*)d_in[7];
    const float* C0  = (const float*)d_in[8];
    const float* C1  = (const float*)d_in[9];
    const float* Cf  = (const float*)d_in[10];
    float* out = (float*)d_out;

    // workspace: TK2 | TC2 | TV2 (float2 tables)
    float2* TK2 = (float2*)d_ws;
    float2* TC2 = TK2 + (size_t)NH*G*HD;
    float2* TV2 = TC2 + (size_t)G*HD;

    build_tables<<<160,      128, 0, stream>>>(K0, K1, C0, C1, V0,
                                               (float*)TK2, (float*)TC2,
                                               (float*)TV2, out);
    mega_attn   <<<Z*NH*NPT, 256, 0, stream>>>(f, xyz, Wq, Kf, Vf, Cf,
                                               TK2, TV2, TC2, out);
}

// Round 9
// 180.816 us; speedup vs baseline: 2.8307x; 2.8307x over previous
//
#include <hip/hip_runtime.h>
#include <math.h>

// Problem constants (fixed by reference)
#define Z 2
#define NPT 256     // points per batch
#define CHN 16      // channels
#define NH 2        // heads
#define NBK 10      // key/conv radial basis
#define HD 100      // radial hidden width
#define NBV 3       // value radial basis
#define G 512       // radial table grid points (all tables ~2 MB, L2-resident)
// Unified table domain [0, VD]. Key/conv radials are exactly 0 beyond
// 5+5/9 (all cosine bases zero); value radial support extends to 7.5.
// At d >= VD all three radials are exactly 0, so the gi>=G-1 clamp is exact.
#define VD 7.5f

typedef float f32x2 __attribute__((ext_vector_type(2)));

__device__ __forceinline__ float swishf(float x) {
    return x / (1.0f + __expf(-x));
}

// ---------------------------------------------------------------------------
// Kernel 1: build radial tables as interleaved float2 {T[g], T[g+1]};
// also zeroes d_out (block 0) — kept harmless (out is fully overwritten by
// conv's direct store, but zeroing costs nothing and keeps options open).
// reps: 0,1 = key heads (2-layer); 2 = conv (2-layer); 3,4 = value (1-layer).
// 16 grid pts per block; grid = 5*32 = 160 blocks x 128 threads.
// ---------------------------------------------------------------------------
__global__ __launch_bounds__(128)
void build_tables(const float* __restrict__ K0, const float* __restrict__ K1,
                  const float* __restrict__ C0, const float* __restrict__ C1,
                  const float* __restrict__ V0,
                  float* __restrict__ TKf, float* __restrict__ TCf,
                  float* __restrict__ TVf) {
    int bid = blockIdx.x;
    int rep = bid >> 5;              // 0..4
    int g0  = (bid & 31) * 16;
    int t   = threadIdx.x;

    if (rep >= 3) {                  // value heads: 1-layer radial
        const float* W0v = V0 + (rep - 3)*NBV*HD;
        float* Tf = TVf + (size_t)(rep - 3)*2*G*HD;
        if (t < HD) {
            #pragma unroll
            for (int k = 0; k < 16; ++k) {
                int gg = g0 + k;
                float d = gg * (VD / (float)(G-1));
                float s = 0.f;
                #pragma unroll
                for (int q = 0; q < NBV; ++q) {
                    float diff = (d - q*2.5f) * 0.4f;
                    float bq = (fabsf(diff) < 1.0f) ? __cosf(1.57079632679f*diff) : 0.f;
                    s += bq * W0v[q*HD + t];
                }
                float v = swishf(s);
                Tf[2*((size_t)gg*HD + t) + 0] = v;
                if (gg > 0) Tf[2*((size_t)(gg-1)*HD + t) + 1] = v;
            }
        }
        return;
    }

    const float* W0 = (rep == 0) ? K0 : (rep == 1) ? (K0 + NBK*HD) : C0;
    const float* W1 = (rep == 0) ? K1 : (rep == 1) ? (K1 + HD*HD)  : C1;
    float* Tf       = (rep == 0) ? TKf : (rep == 1) ? (TKf + 2*(size_t)G*HD) : TCf;

    __shared__ float s_b10[16][NBK];
    __shared__ __align__(16) float s_h1[HD*16];   // [n][k]

    if (t < 16) {
        float d = (g0 + t) * (VD / (float)(G-1));
        #pragma unroll
        for (int q = 0; q < NBK; ++q) {
            float diff = (d - q*(5.0f/9.0f)) * 1.8f;
            s_b10[t][q] = (fabsf(diff) < 1.0f) ? __cosf(1.57079632679f*diff) : 0.f;
        }
    }
    __syncthreads();
    if (t < HD) {
        int n = t;
        float w[NBK];
        #pragma unroll
        for (int q = 0; q < NBK; ++q) w[q] = W0[q*HD + n];
        #pragma unroll
        for (int k = 0; k < 16; ++k) {
            float s = 0.f;
            #pragma unroll
            for (int q = 0; q < NBK; ++q) s += s_b10[k][q] * w[q];
            s_h1[n*16 + k] = swishf(s);
        }
    }
    __syncthreads();
    if (t < HD) {
        int m = t;
        float acc[16];
        #pragma unroll
        for (int k = 0; k < 16; ++k) acc[k] = 0.f;
        const float* w1 = W1 + m;
        #pragma unroll 2
        for (int n = 0; n < HD; ++n) {
            float w = w1[n*HD];                            // coalesced across m
            const float4* hp = (const float4*)&s_h1[n*16]; // broadcast
            float4 x0 = hp[0], x1 = hp[1], x2 = hp[2], x3 = hp[3];
            acc[0]+=x0.x*w;  acc[1]+=x0.y*w;  acc[2]+=x0.z*w;  acc[3]+=x0.w*w;
            acc[4]+=x1.x*w;  acc[5]+=x1.y*w;  acc[6]+=x1.z*w;  acc[7]+=x1.w*w;
            acc[8]+=x2.x*w;  acc[9]+=x2.y*w;  acc[10]+=x2.z*w; acc[11]+=x2.w*w;
            acc[12]+=x3.x*w; acc[13]+=x3.y*w; acc[14]+=x3.z*w; acc[15]+=x3.w*w;
        }
        #pragma unroll
        for (int k = 0; k < 16; ++k) {
            float v = swishf(acc[k]);
            int gg = g0 + k;
            Tf[2*((size_t)gg*HD + m) + 0] = v;
            if (gg > 0) Tf[2*((size_t)(gg-1)*HD + m) + 1] = v;
        }
    }
}

// ---------------------------------------------------------------------------
// Kernel 2: fused q/Gq + scores + softmax + value-U + Vf epilogue.
// One block per (z,h,a) = 1024 blocks x 256 threads. Hot dot products use
// float2 ext-vectors to coax v_pk_fma_f32 (2 FMA/lane/instr on gfx950).
// ---------------------------------------------------------------------------
__global__ __launch_bounds__(256, 4)
void fused_attn(const float* __restrict__ f, const float* __restrict__ xyz,
                const float* __restrict__ Wq, const float* __restrict__ Kf,
                const float* __restrict__ Vf,
                const float2* __restrict__ TK2, const float2* __restrict__ TV2,
                float* __restrict__ attn_h) {
    int bid = blockIdx.x;            // (z*NH + h)*NPT + a
    int a  = bid & 255;
    int zh = bid >> 8;
    int h  = zh & 1;
    int z  = zh >> 1;
    int t  = threadIdx.x;

    __shared__ __align__(16) float s_f[NPT*CHN];   // 16384 B
    __shared__ __align__(16) float s_gu[HD*20];    // 8000 B  gq then U
    __shared__ int   s_gi[NPT];                    // 1024 B
    __shared__ float s_fr[NPT];                    // 1024 B
    __shared__ float s_sc[NPT];                    // 1024 B  scores then p
    __shared__ float s_red[8];
    __shared__ float s_red2[256];                  // q early; Vf partials late

    // phase 1: stage features, per-b geometry, q, gq
    {
        const float4* fz = (const float4*)(f + (size_t)z*NPT*CHN);
        float4* sf = (float4*)s_f;
        for (int i = t; i < NPT*CHN/4; i += 256) sf[i] = fz[i];
    }
    {
        float ax = xyz[(z*NPT + a)*3 + 0];
        float ay = xyz[(z*NPT + a)*3 + 1];
        float az = xyz[(z*NPT + a)*3 + 2];
        int b = t;
        float dx = xyz[(z*NPT + b)*3 + 0] - ax;
        float dy = xyz[(z*NPT + b)*3 + 1] - ay;
        float dz = xyz[(z*NPT + b)*3 + 2] - az;
        float d = sqrtf(dx*dx + dy*dy + dz*dz + 1e-12f);
        float fd = d * ((float)(G-1) / VD);
        int   gi = (int)fd;
        float fr = fd - (float)gi;
        if (gi >= G-1) { gi = G-2; fr = 1.0f; }    // beyond support -> exact 0
        s_gi[b] = gi; s_fr[b] = fr;
    }
    __syncthreads();
    if (t < CHN) {       // q[o] = sum_i f[a,i] * Wq[h][o][i]
        float s = 0.f;
        const float* wq = Wq + (h*CHN + t)*CHN;
        #pragma unroll
        for (int i = 0; i < CHN; ++i) s += s_f[a*CHN + i] * wq[i];
        s_red2[t] = s;
    }
    __syncthreads();
    {   // gq[m][j] = sum_i Kf[h][m][i*16+j] * q[i]
        const float* kf = Kf + (size_t)h*HD*256;
        for (int idx = t; idx < HD*CHN; idx += 256) {
            int m = idx >> 4, j = idx & 15;
            float s = 0.f;
            #pragma unroll
            for (int i = 0; i < CHN; ++i) s += kf[m*256 + i*16 + j] * s_red2[i];
            s_gu[m*20 + j] = s;
        }
    }
    __syncthreads();

    // phase 2: scores. wave w owns b in [w*64, w*64+64); lane covers m, m+64.
    {
        int lane = t & 63, w = t >> 6;
        int m2 = lane + 64;
        bool hasm2 = (m2 < HD);
        f32x2 gq1[8], gq2[8];
        {
            const f32x2* gp = (const f32x2*)&s_gu[lane*20];
            #pragma unroll
            for (int k = 0; k < 8; ++k) gq1[k] = gp[k];
        }
        #pragma unroll
        for (int k = 0; k < 8; ++k) { gq2[k].x = 0.f; gq2[k].y = 0.f; }
        if (hasm2) {
            const f32x2* gp = (const f32x2*)&s_gu[m2*20];
            #pragma unroll
            for (int k = 0; k < 8; ++k) gq2[k] = gp[k];
        }
        const float2* tk = TK2 + (size_t)h*G*HD;
        int bbase = w*64;
        float2 ta0, tb0, ta1, tb1;
        {
            int g0i = s_gi[bbase], g1i = s_gi[bbase+1];
            ta0 = tk[(size_t)g0i*HD + lane];
            tb0 = hasm2 ? tk[(size_t)g0i*HD + m2] : make_float2(0.f, 0.f);
            ta1 = tk[(size_t)g1i*HD + lane];
            tb1 = hasm2 ? tk[(size_t)g1i*HD + m2] : make_float2(0.f, 0.f);
        }
        #pragma unroll 1
        for (int bb = 0; bb < 64; bb += 2) {
            int b0 = bbase + bb, b1 = b0 + 1;
            float fr0 = s_fr[b0], fr1 = s_fr[b1];
            float2 ca0 = ta0, cb0 = tb0, ca1 = ta1, cb1 = tb1;
            if (bb + 2 < 64) {
                int gn0 = s_gi[b0 + 2], gn1 = s_gi[b0 + 3];
                ta0 = tk[(size_t)gn0*HD + lane];
                tb0 = hasm2 ? tk[(size_t)gn0*HD + m2] : make_float2(0.f, 0.f);
                ta1 = tk[(size_t)gn1*HD + lane];
                tb1 = hasm2 ? tk[(size_t)gn1*HD + m2] : make_float2(0.f, 0.f);
            }
            // packed lerps: {row(lane), row(m2)} for each b
            f32x2 tx0; tx0.x = ca0.x; tx0.y = cb0.x;
            f32x2 ty0; ty0.x = ca0.y; ty0.y = cb0.y;
            f32x2 h2p0 = tx0 + fr0*(ty0 - tx0);
            f32x2 tx1; tx1.x = ca1.x; tx1.y = cb1.x;
            f32x2 ty1; ty1.x = ca1.y; ty1.y = cb1.y;
            f32x2 h2p1 = tx1 + fr1*(ty1 - tx1);
            // packed dot products (v_pk_fma_f32 target)
            const f32x2* fq0 = (const f32x2*)&s_f[b0*CHN];
            const f32x2* fq1 = (const f32x2*)&s_f[b1*CHN];
            f32x2 A0 = gq1[0]*fq0[0]; f32x2 B0 = gq2[0]*fq0[0];
            f32x2 A1 = gq1[0]*fq1[0]; f32x2 B1 = gq2[0]*fq1[0];
            #pragma unroll
            for (int k = 1; k < 8; ++k) {
                f32x2 v0 = fq0[k], v1 = fq1[k];
                A0 += gq1[k]*v0;  B0 += gq2[k]*v0;
                A1 += gq1[k]*v1;  B1 += gq2[k]*v1;
            }
            float pp0 = h2p0.x*(A0.x + A0.y) + h2p0.y*(B0.x + B0.y);
            float pp1 = h2p1.x*(A1.x + A1.y) + h2p1.y*(B1.x + B1.y);
            float u0 = __shfl_xor(pp0, 32);
            float u1 = __shfl_xor(pp1, 32);
            float mm = (lane < 32) ? (pp0 + u0) : (pp1 + u1);
            mm += __shfl_xor(mm, 16);
            mm += __shfl_xor(mm, 8);
            mm += __shfl_xor(mm, 4);
            mm += __shfl_xor(mm, 2);
            mm += __shfl_xor(mm, 1);
            if (lane == 0)  s_sc[b0] = mm * (1.0f/16.0f);
            if (lane == 32) s_sc[b1] = mm * (1.0f/16.0f);
        }
    }
    __syncthreads();

    // phase 3: softmax over 256 scores
    {
        float v = s_sc[t];
        float mx = v;
        #pragma unroll
        for (int off = 32; off >= 1; off >>= 1) mx = fmaxf(mx, __shfl_xor(mx, off));
        int wid = t >> 6;
        if ((t & 63) == 0) s_red[wid] = mx;
        __syncthreads();
        mx = fmaxf(fmaxf(s_red[0], s_red[1]), fmaxf(s_red[2], s_red[3]));
        float e = __expf(v - mx);
        float s = e;
        #pragma unroll
        for (int off = 32; off >= 1; off >>= 1) s += __shfl_xor(s, off);
        if ((t & 63) == 0) s_red[4 + wid] = s;
        __syncthreads();
        float tot = s_red[4] + s_red[5] + s_red[6] + s_red[7];
        s_sc[t] = e / tot;
    }
    __syncthreads();

    // phase 4: U[m,j] = sum_b p_b * h1v(d_b)[m] * f[b,j]  via TV lerp (packed)
    {
        int mh = t & 127, half = t >> 7;
        f32x2 U[8];
        #pragma unroll
        for (int k = 0; k < 8; ++k) { U[k].x = 0.f; U[k].y = 0.f; }
        if (mh < HD) {
            const float2* tv = TV2 + (size_t)h*G*HD;
            int bbase = half*128;
            float2 tc = tv[(size_t)s_gi[bbase]*HD + mh];
            #pragma unroll 2
            for (int bb = 0; bb < 128; ++bb) {
                int b = bbase + bb;
                float fr = s_fr[b];
                float2 cur = tc;
                if (bb + 1 < 128) tc = tv[(size_t)s_gi[b+1]*HD + mh];
                float hv = cur.x + fr*(cur.y - cur.x);
                float t1 = s_sc[b] * hv;
                const f32x2* fp = (const f32x2*)&s_f[b*CHN];
                #pragma unroll
                for (int k = 0; k < 8; ++k) U[k] += fp[k]*t1;
            }
        }
        if (half == 1 && mh < HD) {
            f32x2* gu = (f32x2*)&s_gu[mh*20];
            #pragma unroll
            for (int k = 0; k < 8; ++k) gu[k] = U[k];
        }
        __syncthreads();
        if (half == 0 && mh < HD) {
            f32x2* gu = (f32x2*)&s_gu[mh*20];
            #pragma unroll
            for (int k = 0; k < 8; ++k) gu[k] += U[k];
        }
    }
    __syncthreads();
    {   // epilogue: attn_h[bid][i] = sum_{m,j} U[m,j] * Vf[h][m][i*16+j]  (packed)
        int i = t & 15, ms = t >> 4;
        f32x2 acc2; acc2.x = 0.f; acc2.y = 0.f;
        for (int m = ms; m < HD; m += 16) {
            const f32x2* vf = (const f32x2*)(Vf + ((size_t)h*HD + m)*256 + i*16);
            const f32x2* Um = (const f32x2*)&s_gu[m*20];
            #pragma unroll
            for (int k = 0; k < 8; ++k) acc2 += Um[k]*vf[k];
        }
        s_red2[ms*16 + i] = acc2.x + acc2.y;
    }
    __syncthreads();
    if (t < 16) {
        float s = 0.f;
        #pragma unroll
        for (int ms = 0; ms < 16; ++ms) s += s_red2[ms*16 + t];
        attn_h[(size_t)bid*CHN + t] = s;
    }
}

// ---------------------------------------------------------------------------
// Kernel 3: final conv, one block per (z,a) = 512 blocks, 256 threads.
// Full 256-b accumulation, direct store (no atomics). Packed U/Cf loops.
// ---------------------------------------------------------------------------
__global__ __launch_bounds__(256)
void conv_kernel(const float* __restrict__ xyz, const float2* __restrict__ TC2,
                 const float* __restrict__ Cf, const float* __restrict__ attn_h,
                 float* __restrict__ out) {
    int za = blockIdx.x;
    int z  = za >> 8;
    int t  = threadIdx.x;

    __shared__ __align__(16) float s_ao[NPT*CHN];  // 16384 B head-summed attn
    __shared__ __align__(16) float s_U[HD*20];     // 8000 B
    __shared__ int   s_gi[NPT];
    __shared__ float s_fr[NPT];
    __shared__ float s_red2[256];

    for (int idx = t; idx < NPT*CHN; idx += 256) {
        s_ao[idx] = attn_h[(size_t)(z*NH + 0)*NPT*CHN + idx]
                  + attn_h[(size_t)(z*NH + 1)*NPT*CHN + idx];
    }
    {
        int b = t;
        float dx = xyz[(z*NPT+b)*3+0] - xyz[za*3+0];
        float dy = xyz[(z*NPT+b)*3+1] - xyz[za*3+1];
        float dz = xyz[(z*NPT+b)*3+2] - xyz[za*3+2];
        float d = sqrtf(dx*dx + dy*dy + dz*dz + 1e-12f);
        float fd = d * ((float)(G-1) / VD);
        int   gi = (int)fd;
        float fr = fd - (float)gi;
        if (gi >= G-1) { gi = G-2; fr = 1.0f; }
        s_gi[b] = gi; s_fr[b] = fr;
    }
    __syncthreads();
    int mh = t & 127, half = t >> 7;
    f32x2 U[8];
    #pragma unroll
    for (int k = 0; k < 8; ++k) { U[k].x = 0.f; U[k].y = 0.f; }
    if (mh < HD) {
        int lb = half*128;
        float2 tc = TC2[(size_t)s_gi[lb]*HD + mh];
        #pragma unroll 2
        for (int bb = 0; bb < 128; ++bb) {
            int bl = lb + bb;
            float fr = s_fr[bl];
            float2 cur = tc;
            if (bb + 1 < 128) tc = TC2[(size_t)s_gi[bl+1]*HD + mh];
            float h2 = cur.x + fr*(cur.y - cur.x);
            const f32x2* ap = (const f32x2*)&s_ao[bl*CHN];
            #pragma unroll
            for (int k = 0; k < 8; ++k) U[k] += ap[k]*h2;
        }
    }
    if (half == 1 && mh < HD) {
        f32x2* su = (f32x2*)&s_U[mh*20];
        #pragma unroll
        for (int k = 0; k < 8; ++k) su[k] = U[k];
    }
    __syncthreads();
    if (half == 0 && mh < HD) {
        f32x2* su = (f32x2*)&s_U[mh*20];
        #pragma unroll
        for (int k = 0; k < 8; ++k) su[k] += U[k];
    }
    __syncthreads();
    {
        int i = t & 15, ms = t >> 4;
        f32x2 acc2; acc2.x = 0.f; acc2.y = 0.f;
        for (int m = ms; m < HD; m += 16) {
            const f32x2* cf = (const f32x2*)(Cf + (size_t)m*256 + i*16);
            const f32x2* Um = (const f32x2*)&s_U[m*20];
            #pragma unroll
            for (int k = 0; k < 8; ++k) acc2 += Um[k]*cf[k];
        }
        s_red2[ms*16 + i] = acc2.x + acc2.y;
    }
    __syncthreads();
    if (t < 16) {
        float s = 0.f;
        #pragma unroll
        for (int ms = 0; ms < 16; ++ms) s += s_red2[ms*16 + t];
        out[(size_t)za*CHN + t] = s;
    }
}

// ---------------------------------------------------------------------------
extern "C" void kernel_launch(void* const* d_in, const int* in_sizes, int n_in,
                              void* d_out, int out_size, void* d_ws, size_t ws_size,
                              hipStream_t stream) {
    const float* f   = (const float*)d_in[0];
    const float* xyz = (const float*)d_in[1];
    const float* Wq  = (const float*)d_in[2];
    const float* K0  = (const float*)d_in[3];
    const float* K1  = (const float*)d_in[4];
    const float* Kf  = (const float*)d_in[5];
    const float* V0  = (const float*)d_in[6];
    const float* Vf  = (const float*)d_in[7];
    const float* C0  = (const float*)d_in[8];
    const float* C1  = (const float*)d_in[9];
    const float* Cf  = (const float*)d_in[10];
    float* out = (float*)d_out;

    // workspace: TK2 | TC2 | TV2 (float2 tables) | attn_h
    float2* TK2    = (float2*)d_ws;
    float2* TC2    = TK2 + (size_t)NH*G*HD;
    float2* TV2    = TC2 + (size_t)G*HD;
    float*  attn_h = (float*)(TV2 + (size_t)NH*G*HD);

    build_tables<<<160,      128, 0, stream>>>(K0, K1, C0, C1, V0,
                                               (float*)TK2, (float*)TC2,
                                               (float*)TV2);
    fused_attn  <<<Z*NH*NPT, 256, 0, stream>>>(f, xyz, Wq, Kf, Vf, TK2, TV2, attn_h);
    conv_kernel <<<Z*NPT,    256, 0, stream>>>(xyz, TC2, Cf, attn_h, out);
}